// Round 6
// baseline (4336.224 us; speedup 1.0000x reference)
//
#include <hip/hip_runtime.h>
#include <hip/hip_bf16.h>
#include <math.h>

#define N_USERS 50000
#define N_ITEMS 30000
#define N_ENT   100000
#define NE      500000      // KG edges E
#define NEI     1000000     // interaction edges EI
#define D       64
#define GAMMA   0.2f

typedef __hip_bfloat16 bf16;

__device__ __forceinline__ float wave_sum(float v) {
    #pragma unroll
    for (int off = 32; off > 0; off >>= 1) v += __shfl_xor(v, off, 64);
    return v;
}

__device__ __forceinline__ float g16_sum(float v) {
    #pragma unroll
    for (int off = 1; off < 16; off <<= 1) v += __shfl_xor(v, off, 64);
    return v;
}

__device__ __forceinline__ float bits2f(unsigned short u) {
    return __uint_as_float(((unsigned)u) << 16);
}

__device__ __forceinline__ unsigned short f2bf_bits(float f) {
    bf16 b = __float2bfloat16(f);
    return *(unsigned short*)&b;
}

__device__ __forceinline__ float sigmoidf(float x) { return 1.0f / (1.0f + expf(-x)); }

__device__ __forceinline__ float n2n(float y) {
    if (isnan(y)) return 0.0f;
    if (isinf(y)) return y > 0.0f ? 1e4f : 1e-4f;
    return y;
}

// ================= CSR build (fused U+H) =================
__global__ void k_hist2(const int* __restrict__ ie, const int* __restrict__ eidx,
                        int* __restrict__ cntU, int* __restrict__ cntH) {
    int e = blockIdx.x * blockDim.x + threadIdx.x;
    if (e < NEI) atomicAdd(&cntU[ie[e]], 1);
    else if (e < NEI + NE) atomicAdd(&cntH[eidx[e - NEI]], 1);
}

// chunk = 1024 per block; blocks [0,nbU) -> U, rest -> H
__global__ void k_scan1(const int* __restrict__ cntU_, int* __restrict__ offU_,
                        int* __restrict__ bsumU_, int nU, int nbU,
                        const int* __restrict__ cntH_, int* __restrict__ offH_,
                        int* __restrict__ bsumH_, int nH) {
    __shared__ int sh[256];
    int t = threadIdx.x;
    int b = blockIdx.x;
    const int* cnt; int* off; int* bsum; int n; int lb;
    if (b < nbU) { cnt = cntU_; off = offU_; bsum = bsumU_; n = nU; lb = b; }
    else         { cnt = cntH_; off = offH_; bsum = bsumH_; n = nH; lb = b - nbU; }
    int base = lb * 1024 + t * 4;
    int v[4];
    #pragma unroll
    for (int j = 0; j < 4; j++) v[j] = (base + j < n) ? cnt[base + j] : 0;
    int tot = v[0] + v[1] + v[2] + v[3];
    sh[t] = tot;
    __syncthreads();
    for (int d = 1; d < 256; d <<= 1) {
        int x = (t >= d) ? sh[t - d] : 0;
        __syncthreads();
        sh[t] += x;
        __syncthreads();
    }
    int run = sh[t] - tot;
    #pragma unroll
    for (int j = 0; j < 4; j++) {
        if (base + j < n) off[base + j] = run;
        run += v[j];
    }
    if (t == 255) bsum[lb] = sh[255];
}

// block 0: U block sums, block 1: H block sums
__global__ void k_scan2(const int* __restrict__ bsumU_, int* __restrict__ bsxU_, int nbU,
                        const int* __restrict__ bsumH_, int* __restrict__ bsxH_, int nbH) {
    __shared__ int sh[256];
    int t = threadIdx.x;
    const int* bsum; int* bsx; int nb;
    if (blockIdx.x == 0) { bsum = bsumU_; bsx = bsxU_; nb = nbU; }
    else                 { bsum = bsumH_; bsx = bsxH_; nb = nbH; }
    int v = (t < nb) ? bsum[t] : 0;
    sh[t] = v;
    __syncthreads();
    for (int d = 1; d < 256; d <<= 1) {
        int x = (t >= d) ? sh[t - d] : 0;
        __syncthreads();
        sh[t] += x;
        __syncthreads();
    }
    if (t < nb) bsx[t] = sh[t] - v;
    if (t == 255) bsx[nb] = sh[255];
}

__global__ void k_scan3(int* __restrict__ offU_, int* __restrict__ curU_,
                        const int* __restrict__ bsxU_, int nU, int nbU, int blocksU,
                        int* __restrict__ offH_, int* __restrict__ curH_,
                        const int* __restrict__ bsxH_, int nH, int nbH) {
    int b = blockIdx.x;
    int* off; int* cur; const int* bsx; int n; int nb; int i;
    if (b < blocksU) { off = offU_; cur = curU_; bsx = bsxU_; n = nU; nb = nbU; i = b * 256 + threadIdx.x; }
    else             { off = offH_; cur = curH_; bsx = bsxH_; n = nH; nb = nbH; i = (b - blocksU) * 256 + threadIdx.x; }
    if (i > n) return;
    int val = (i == n) ? bsx[nb] : off[i] + bsx[i >> 10];
    off[i] = val;
    if (i < n) cur[i] = val;
}

// fused scatter: U edges -> packed int2(it, wbits); KG edges -> packed (t|r<<20)
__global__ void k_scatter(const int* __restrict__ ie, const float* __restrict__ w,
                          const int* __restrict__ eidx, const int* __restrict__ etype,
                          int* __restrict__ curU, int* __restrict__ curH,
                          int2* __restrict__ itw, int* __restrict__ csr_tr) {
    int e = blockIdx.x * blockDim.x + threadIdx.x;
    if (e < NEI) {
        int u = ie[e];
        int pos = atomicAdd(&curU[u], 1);
        itw[pos] = make_int2(ie[NEI + e], __float_as_int(w[e]));
    } else if (e < NEI + NE) {
        int e2 = e - NEI;
        int h = eidx[e2];
        int pos = atomicAdd(&curH[h], 1);
        csr_tr[pos] = eidx[NE + e2] | ((etype[e2] - 1) << 20);
    }
}

// ================= lane-owns-row tiled GEMM helpers =================
__device__ __forceinline__ void stage_rows2(const float* __restrict__ s0,
                                            const float* __restrict__ s1,
                                            float* At, int row0, int n, int t) {
    #pragma unroll
    for (int half = 0; half < 2; half++) {
        const float* src = half ? s1 : s0;
        int kofs = half ? 32 : 0;
        #pragma unroll
        for (int fi = t, it = 0; it < 2; fi += 256, it++) {
            int row = fi >> 3;
            int k4 = (fi & 7) << 2;
            float4 v = make_float4(0.f, 0.f, 0.f, 0.f);
            if (row0 + row < n) v = *(const float4*)&src[(size_t)(row0 + row) * 32 + k4];
            At[(kofs + k4 + 0) * 64 + row] = v.x;
            At[(kofs + k4 + 1) * 64 + row] = v.y;
            At[(kofs + k4 + 2) * 64 + row] = v.z;
            At[(kofs + k4 + 3) * 64 + row] = v.w;
        }
    }
}

__device__ __forceinline__ void stage_rows1(const float* __restrict__ src,
                                            float* At, int row0, int n, int t) {
    #pragma unroll
    for (int fi = t, it = 0; it < 4; fi += 256, it++) {
        int row = fi >> 4;
        int k4 = (fi & 15) << 2;
        float4 v = make_float4(0.f, 0.f, 0.f, 0.f);
        if (row0 + row < n) v = *(const float4*)&src[(size_t)(row0 + row) * 64 + k4];
        At[(k4 + 0) * 64 + row] = v.x;
        At[(k4 + 1) * 64 + row] = v.y;
        At[(k4 + 2) * 64 + row] = v.z;
        At[(k4 + 3) * 64 + row] = v.w;
    }
}

// fused: blocks [0,IB) item proj (Ik bf16 + Iv), [IB, IB+UB) user proj (Uq)
__global__ __launch_bounds__(256) void k_proj(const float* __restrict__ I,
        const float* __restrict__ Wk, const float* __restrict__ Wv,
        const float* __restrict__ UE, const float* __restrict__ Wq,
        bf16* __restrict__ IkB, float* __restrict__ Iv, float* __restrict__ Uq, int IB) {
    __shared__ float At[64 * 64];
    int t = threadIdx.x;
    int b = blockIdx.x;
    int lane = t & 63;
    int wv = __builtin_amdgcn_readfirstlane(t >> 6);
    if (b < IB) {
        int row0 = b << 6;
        stage_rows1(I, At, row0, N_ITEMS, t);
        __syncthreads();
        const float* Wb = ((wv >> 1) ? Wv : Wk) + (wv & 1) * 32;
        float acc[32];
        #pragma unroll
        for (int c = 0; c < 32; c++) acc[c] = 0.f;
        for (int k = 0; k < 64; k++) {
            float a = At[k * 64 + lane];
            const float* wr = Wb + k * 64;
            #pragma unroll
            for (int c4 = 0; c4 < 8; c4++) {
                float4 w4 = *(const float4*)&wr[c4 * 4];
                acc[c4 * 4 + 0] += a * w4.x;
                acc[c4 * 4 + 1] += a * w4.y;
                acc[c4 * 4 + 2] += a * w4.z;
                acc[c4 * 4 + 3] += a * w4.w;
            }
        }
        int row = row0 + lane;
        if (row < N_ITEMS) {
            if (wv >> 1) {
                float* dst = Iv + (size_t)row * 64 + (wv & 1) * 32;
                #pragma unroll
                for (int c4 = 0; c4 < 8; c4++)
                    *(float4*)&dst[c4 * 4] = make_float4(acc[c4*4], acc[c4*4+1], acc[c4*4+2], acc[c4*4+3]);
            } else {
                bf16* dst = IkB + (size_t)row * 64 + (wv & 1) * 32;
                #pragma unroll
                for (int c4 = 0; c4 < 8; c4++) {
                    ushort4 s;
                    s.x = f2bf_bits(acc[c4 * 4 + 0]);
                    s.y = f2bf_bits(acc[c4 * 4 + 1]);
                    s.z = f2bf_bits(acc[c4 * 4 + 2]);
                    s.w = f2bf_bits(acc[c4 * 4 + 3]);
                    *(ushort4*)&dst[c4 * 4] = s;
                }
            }
        }
    } else {
        int row0 = (b - IB) << 6;
        stage_rows1(UE, At, row0, N_USERS, t);
        __syncthreads();
        const float* Wb = Wq + wv * 16;
        float acc[16];
        #pragma unroll
        for (int c = 0; c < 16; c++) acc[c] = 0.f;
        for (int k = 0; k < 64; k++) {
            float a = At[k * 64 + lane];
            const float* wr = Wb + k * 64;
            #pragma unroll
            for (int c4 = 0; c4 < 4; c4++) {
                float4 w4 = *(const float4*)&wr[c4 * 4];
                acc[c4 * 4 + 0] += a * w4.x;
                acc[c4 * 4 + 1] += a * w4.y;
                acc[c4 * 4 + 2] += a * w4.z;
                acc[c4 * 4 + 3] += a * w4.w;
            }
        }
        int row = row0 + lane;
        if (row < N_USERS) {
            float* dst = Uq + (size_t)row * 64 + wv * 16;
            #pragma unroll
            for (int c4 = 0; c4 < 4; c4++)
                *(float4*)&dst[c4 * 4] = make_float4(acc[c4*4], acc[c4*4+1], acc[c4*4+2], acc[c4*4+3]);
        }
    }
}

// ================= Stage A fused edge kernel =================
__global__ void k_userAB(const int* __restrict__ offU, const int2* __restrict__ itw,
                         const float* __restrict__ Uq, const bf16* __restrict__ IkB,
                         float* __restrict__ exA, float* __restrict__ c, int n) {
    int u = (blockIdx.x * blockDim.x + threadIdx.x) >> 6;
    int lane = threadIdx.x & 63;
    if (u >= n) return;
    int s = offU[u], e = offU[u + 1];
    if (s == e) return;
    int l = lane & 15, g = lane >> 4;
    float4 qv = *(const float4*)&Uq[(size_t)u * D + l * 4];
    float den = 0.f;
    for (int j0 = s; j0 < e; j0 += 4) {
        int j = j0 + g;
        bool valid = j < e;
        int jj = valid ? j : s;
        int2 iw = itw[jj];
        ushort4 ik = *(const ushort4*)&IkB[(size_t)iw.x * D + l * 4];
        float d = qv.x * bits2f(ik.x) + qv.y * bits2f(ik.y) +
                  qv.z * bits2f(ik.z) + qv.w * bits2f(ik.w);
        float sc = g16_sum(d);
        float ex = valid ? expf(sc * 0.125f * __int_as_float(iw.y)) : 0.f;
        den += ex;
        if (valid && l == 0) exA[j] = ex;
    }
    den += __shfl_xor(den, 16, 64);
    den += __shfl_xor(den, 32, 64);
    float inv = 1.0f / (den * (float)(e - s));
    __threadfence();   // make exA stores visible to all lanes of this wave
    for (int j = s + lane; j < e; j += 64)
        atomicAdd(&c[itw[j].x], exA[j] * inv);
}

__global__ void k_pdense(const float* __restrict__ c, const float* __restrict__ Iv,
                         float* __restrict__ p, int n) {
    int lane = threadIdx.x & 63;
    int gw = blockIdx.x * 4 + (threadIdx.x >> 6);
    int nw = gridDim.x * 4;
    float acc = 0.f;
    for (int i = gw; i < n; i += nw) acc += c[i] * Iv[(size_t)i * D + lane];
    __shared__ float red[256];
    red[threadIdx.x] = acc;
    __syncthreads();
    if (threadIdx.x < 64) {
        float s = red[threadIdx.x] + red[threadIdx.x + 64] + red[threadIdx.x + 128] + red[threadIdx.x + 192];
        atomicAdd(&p[threadIdx.x], s);
    }
}

// ================= Stage B: ent_ab + rel_tables + v2 in one dispatch =================
__global__ __launch_bounds__(256) void k_entabx(const float* __restrict__ er,
        const float* __restrict__ ei, const float* __restrict__ fpW1,
        const float* __restrict__ rr, const float* __restrict__ ri,
        const float* __restrict__ rtW1, const float* __restrict__ rtW2,
        const float* __restrict__ rt_b2, const float* __restrict__ p,
        float* __restrict__ EH, float* __restrict__ ET,
        float* __restrict__ RR1, float* __restrict__ PSI,
        float* __restrict__ v2, float* __restrict__ cb, int EB) {
    __shared__ float At[64 * 64];
    int b = blockIdx.x;
    int t = threadIdx.x;
    if (b < EB) {
        int row0 = b << 6;
        stage_rows2(er, ei, At, row0, N_ENT, t);
        __syncthreads();
        int lane = t & 63;
        int wv = __builtin_amdgcn_readfirstlane(t >> 6);
        const float* Wb = fpW1 + ((wv >> 1) ? (128 * 64) : 0) + (wv & 1) * 32;
        float acc[32];
        #pragma unroll
        for (int c = 0; c < 32; c++) acc[c] = 0.f;
        for (int k = 0; k < 64; k++) {
            float a = At[k * 64 + lane];
            const float* wr = Wb + k * 64;
            #pragma unroll
            for (int c4 = 0; c4 < 8; c4++) {
                float4 w4 = *(const float4*)&wr[c4 * 4];
                acc[c4 * 4 + 0] += a * w4.x;
                acc[c4 * 4 + 1] += a * w4.y;
                acc[c4 * 4 + 2] += a * w4.z;
                acc[c4 * 4 + 3] += a * w4.w;
            }
        }
        int row = row0 + lane;
        if (row < N_ENT) {
            float* dst = ((wv >> 1) ? ET : EH) + (size_t)row * 64 + (wv & 1) * 32;
            #pragma unroll
            for (int c4 = 0; c4 < 8; c4++)
                *(float4*)&dst[c4 * 4] = make_float4(acc[c4*4], acc[c4*4+1], acc[c4*4+2], acc[c4*4+3]);
        }
    } else if (b == EB) {
        if (t < 64) {
            int lane = t;
            for (int r = 0; r < 10; r++) {
                float a = 0.f, bb = 0.f;
                for (int k = 0; k < 32; k++) {
                    float sr = rr[r * 32 + k], si = ri[r * 32 + k];
                    a  += sr * fpW1[(64 + k) * D + lane] + si * fpW1[(96 + k) * D + lane];
                    bb += sr * rtW1[k * D + lane] + si * rtW1[(32 + k) * D + lane];
                }
                RR1[r * D + lane] = a;
                PSI[r * D + lane] = bb;
            }
        }
    } else {
        if (t < 64) {
            int j = t;
            float acc = 0.f;
            #pragma unroll
            for (int k = 0; k < D; k++) acc += rtW2[j * D + k] * p[k];
            v2[j] = acc;
            float cc = rt_b2[j] * p[j];
            cc = wave_sum(cc);
            if (j == 0) cb[0] = cc;
        }
    }
}

// PHI = [er|ei]@rtW1
__global__ __launch_bounds__(256) void k_ent_phi(const float* __restrict__ er,
        const float* __restrict__ ei, const float* __restrict__ rtW1,
        float* __restrict__ PHI, int n) {
    __shared__ float At[64 * 64];
    int t = threadIdx.x;
    int row0 = blockIdx.x << 6;
    stage_rows2(er, ei, At, row0, n, t);
    __syncthreads();
    int lane = t & 63;
    int wv = __builtin_amdgcn_readfirstlane(t >> 6);
    const float* Wb = rtW1 + wv * 16;
    float acc[16];
    #pragma unroll
    for (int c = 0; c < 16; c++) acc[c] = 0.f;
    for (int k = 0; k < 64; k++) {
        float a = At[k * 64 + lane];
        const float* wr = Wb + k * 64;
        #pragma unroll
        for (int c4 = 0; c4 < 4; c4++) {
            float4 w4 = *(const float4*)&wr[c4 * 4];
            acc[c4 * 4 + 0] += a * w4.x;
            acc[c4 * 4 + 1] += a * w4.y;
            acc[c4 * 4 + 2] += a * w4.z;
            acc[c4 * 4 + 3] += a * w4.w;
        }
    }
    int row = row0 + lane;
    if (row < n) {
        float* dst = PHI + (size_t)row * 64 + wv * 16;
        #pragma unroll
        for (int c4 = 0; c4 < 4; c4++)
            *(float4*)&dst[c4 * 4] = make_float4(acc[c4*4], acc[c4*4+1], acc[c4*4+2], acc[c4*4+3]);
    }
}

// wave/head, 16-lane subgroups, 4 edges in flight: gate weights
__global__ void k_omega1(const int* __restrict__ offH, const int* __restrict__ csr_tr,
                         const float* __restrict__ EH, const float* __restrict__ ET,
                         const float* __restrict__ RR1, const float* __restrict__ fp_b1,
                         const float* __restrict__ fpW2, const float* __restrict__ fp_b2,
                         float* __restrict__ w0a, float* __restrict__ w1a,
                         float* __restrict__ w2a, int n) {
    int h = (blockIdx.x * blockDim.x + threadIdx.x) >> 6;
    int lane = threadIdx.x & 63;
    if (h >= n) return;
    int s = offH[h], e = offH[h + 1];
    if (s == e) return;
    int l = lane & 15, g = lane >> 4;
    int d0 = l * 4;
    float4 ehh = *(const float4*)&EH[(size_t)h * D + d0];
    float4 b1 = *(const float4*)&fp_b1[d0];
    ehh.x += b1.x; ehh.y += b1.y; ehh.z += b1.z; ehh.w += b1.w;
    float f0[4], f1[4], f2[4];
    #pragma unroll
    for (int cc = 0; cc < 4; cc++) {
        f0[cc] = fpW2[(d0 + cc) * 3 + 0];
        f1[cc] = fpW2[(d0 + cc) * 3 + 1];
        f2[cc] = fpW2[(d0 + cc) * 3 + 2];
    }
    float b20 = fp_b2[0], b21 = fp_b2[1], b22 = fp_b2[2];
    for (int j0 = s; j0 < e; j0 += 4) {
        int j = j0 + g;
        bool valid = j < e;
        int jj = valid ? j : s;
        int pk = csr_tr[jj];
        int t = pk & 0xFFFFF, r = pk >> 20;
        float4 et = *(const float4*)&ET[(size_t)t * D + d0];
        float4 rr = *(const float4*)&RR1[r * D + d0];
        float z0 = sigmoidf(ehh.x + rr.x + et.x);
        float z1 = sigmoidf(ehh.y + rr.y + et.y);
        float z2 = sigmoidf(ehh.z + rr.z + et.z);
        float z3 = sigmoidf(ehh.w + rr.w + et.w);
        float a0 = z0 * f0[0] + z1 * f0[1] + z2 * f0[2] + z3 * f0[3];
        float a1 = z0 * f1[0] + z1 * f1[1] + z2 * f1[2] + z3 * f1[3];
        float a2 = z0 * f2[0] + z1 * f2[1] + z2 * f2[2] + z3 * f2[3];
        a0 = g16_sum(a0); a1 = g16_sum(a1); a2 = g16_sum(a2);
        if (valid && l == 0) {
            a0 += b20; a1 += b21; a2 += b22;
            float mx = fmaxf(a0, fmaxf(a1, a2));
            float e0 = expf(a0 - mx), e1 = expf(a1 - mx), e2 = expf(a2 - mx);
            float inv = 1.0f / (e0 + e1 + e2);
            w0a[j] = e0 * inv;
            w1a[j] = e1 * inv;
            w2a[j] = e2 * inv;
        }
    }
}

// fused omega2 (omega + alpha + eta, wave-local) + cvt blocks (entity_emb -> eA bf16)
__global__ void k_omega2cvt(const int* __restrict__ offH, const int* __restrict__ csr_tr,
                            const float* __restrict__ PHI, const float* __restrict__ PSI,
                            const float* __restrict__ rt_b1, const float* __restrict__ v2,
                            const float* __restrict__ cb, const float* __restrict__ w0a,
                            const float* __restrict__ w1a, const float* __restrict__ w2a,
                            float* __restrict__ omg, float* __restrict__ csr_a,
                            float* __restrict__ csr_et,
                            const float* __restrict__ src_emb, bf16* __restrict__ eA,
                            int OB, int n) {
    int b = blockIdx.x;
    if (b >= OB) {
        int base = (b - OB) * 1024 + threadIdx.x * 4;
        float4 v = *(const float4*)&src_emb[base];
        ushort4 s;
        s.x = f2bf_bits(v.x); s.y = f2bf_bits(v.y);
        s.z = f2bf_bits(v.z); s.w = f2bf_bits(v.w);
        *(ushort4*)&eA[base] = s;
        return;
    }
    int h = (b * blockDim.x + threadIdx.x) >> 6;
    int lane = threadIdx.x & 63;
    if (h >= n) return;
    int s = offH[h], e = offH[h + 1];
    if (s == e) return;
    int l = lane & 15, g = lane >> 4;
    int d0 = l * 4;
    float4 phh = *(const float4*)&PHI[(size_t)h * D + d0];
    float4 rb = *(const float4*)&rt_b1[d0];
    float4 vv = *(const float4*)&v2[d0];
    float cc = cb[0];
    float so = 0.f;
    for (int j0 = s; j0 < e; j0 += 4) {
        int j = j0 + g;
        bool valid = j < e;
        int jj = valid ? j : s;
        int pk = csr_tr[jj];
        int t = pk & 0xFFFFF, r = pk >> 20;
        float W0 = w0a[jj], W1 = w1a[jj], W2 = w2a[jj];
        float4 pt = *(const float4*)&PHI[(size_t)t * D + d0];
        float4 ps = *(const float4*)&PSI[r * D + d0];
        float sv = sigmoidf(W0 * phh.x + W1 * ps.x + W2 * pt.x + rb.x) * vv.x
                 + sigmoidf(W0 * phh.y + W1 * ps.y + W2 * pt.y + rb.y) * vv.y
                 + sigmoidf(W0 * phh.z + W1 * ps.z + W2 * pt.z + rb.z) * vv.z
                 + sigmoidf(W0 * phh.w + W1 * ps.w + W2 * pt.w + rb.w) * vv.w;
        sv = g16_sum(sv);
        float om = (sv + cc) * 0.125f;
        if (valid) {
            if (l == 0) omg[j] = om;
            so += om;
        }
    }
    so += __shfl_xor(so, 16, 64);
    so += __shfl_xor(so, 32, 64);
    float invO = 1.0f / (so + 1e-8f);
    __threadfence();   // make omg stores visible to all lanes of this wave
    float se = 0.f;
    for (int j = s + lane; j < e; j += 64) {
        float a = omg[j] * invO;
        csr_a[j] = a;
        se += (a > GAMMA) ? a : 0.0f;
    }
    se = wave_sum(se);
    float invE = 1.0f / (se + 1e-8f);
    for (int j = s + lane; j < e; j += 64) {
        float a = csr_a[j];
        csr_et[j] = ((a > GAMMA) ? a : 0.0f) * invE;
    }
}

// ================= fused hop: blocks [0,EB) entity side, rest user side =================
__global__ void k_hop(const int* __restrict__ offH, const int* __restrict__ tr,
                      const float* __restrict__ rho, const float* __restrict__ rel,
                      const int* __restrict__ offU, const int2* __restrict__ itw,
                      const bf16* __restrict__ ecur, bf16* __restrict__ enxt,
                      const float* __restrict__ initE, const float* __restrict__ initU,
                      float* __restrict__ outE, float* __restrict__ outU,
                      int init, int EB) {
    int b = blockIdx.x;
    int lane = threadIdx.x & 63;
    int l = lane & 15, g = lane >> 4;
    int d0 = l * 4;
    if (b < EB) {
        int gw = b * 4 + (threadIdx.x >> 6);
        if (gw >= N_ENT) return;
        int s = offH[gw], e = offH[gw + 1];
        float a0 = 0.f, a1 = 0.f, a2 = 0.f, a3 = 0.f;
        for (int j0 = s; j0 < e; j0 += 4) {
            int j = j0 + g;
            bool valid = j < e;
            int jj = valid ? j : s;
            int pk = tr[jj];
            int t = pk & 0xFFFFF, r = pk >> 20;
            float rh = valid ? rho[jj] : 0.f;
            ushort4 ev = *(const ushort4*)&ecur[(size_t)t * D + d0];
            float4 rl = *(const float4*)&rel[r * D + d0];
            a0 += rh * bits2f(ev.x) * rl.x;
            a1 += rh * bits2f(ev.y) * rl.y;
            a2 += rh * bits2f(ev.z) * rl.z;
            a3 += rh * bits2f(ev.w) * rl.w;
        }
        a0 += __shfl_xor(a0, 16, 64); a0 += __shfl_xor(a0, 32, 64);
        a1 += __shfl_xor(a1, 16, 64); a1 += __shfl_xor(a1, 32, 64);
        a2 += __shfl_xor(a2, 16, 64); a2 += __shfl_xor(a2, 32, 64);
        a3 += __shfl_xor(a3, 16, 64); a3 += __shfl_xor(a3, 32, 64);
        float invd = 1.0f / fmaxf((float)(e - s), 1.0f);
        a0 *= invd; a1 *= invd; a2 *= invd; a3 *= invd;
        float ss = a0 * a0 + a1 * a1 + a2 * a2 + a3 * a3;
        ss = g16_sum(ss);
        float nrm = fmaxf(sqrtf(ss), 1e-8f);
        float y0 = n2n(a0 / nrm), y1 = n2n(a1 / nrm), y2 = n2n(a2 / nrm), y3 = n2n(a3 / nrm);
        if (g == 0) {
            ushort4 st;
            st.x = f2bf_bits(y0); st.y = f2bf_bits(y1); st.z = f2bf_bits(y2); st.w = f2bf_bits(y3);
            *(ushort4*)&enxt[(size_t)gw * D + d0] = st;
            size_t o = (size_t)gw * D + d0;
            float4 prev;
            if (init) prev = *(const float4*)&initE[o];
            else      prev = *(const float4*)&outE[o];
            *(float4*)&outE[o] = make_float4(prev.x + y0, prev.y + y1, prev.z + y2, prev.w + y3);
        }
    } else {
        int gw = (b - EB) * 4 + (threadIdx.x >> 6);
        if (gw >= N_USERS) return;
        int s = offU[gw], e = offU[gw + 1];
        float a0 = 0.f, a1 = 0.f, a2 = 0.f, a3 = 0.f;
        for (int j0 = s; j0 < e; j0 += 4) {
            int j = j0 + g;
            bool valid = j < e;
            int jj = valid ? j : s;
            int2 iw = itw[jj];
            float w = valid ? __int_as_float(iw.y) : 0.f;
            ushort4 ev = *(const ushort4*)&ecur[(size_t)iw.x * D + d0];
            a0 += w * bits2f(ev.x);
            a1 += w * bits2f(ev.y);
            a2 += w * bits2f(ev.z);
            a3 += w * bits2f(ev.w);
        }
        a0 += __shfl_xor(a0, 16, 64); a0 += __shfl_xor(a0, 32, 64);
        a1 += __shfl_xor(a1, 16, 64); a1 += __shfl_xor(a1, 32, 64);
        a2 += __shfl_xor(a2, 16, 64); a2 += __shfl_xor(a2, 32, 64);
        a3 += __shfl_xor(a3, 16, 64); a3 += __shfl_xor(a3, 32, 64);
        float ss = a0 * a0 + a1 * a1 + a2 * a2 + a3 * a3;
        ss = g16_sum(ss);
        float nrm = fmaxf(sqrtf(ss), 1e-8f);
        float y0 = n2n(a0 / nrm), y1 = n2n(a1 / nrm), y2 = n2n(a2 / nrm), y3 = n2n(a3 / nrm);
        if (g == 0) {
            size_t o = (size_t)gw * D + d0;
            float4 prev;
            if (init) prev = *(const float4*)&initU[o];
            else      prev = *(const float4*)&outU[o];
            *(float4*)&outU[o] = make_float4(prev.x + y0, prev.y + y1, prev.z + y2, prev.w + y3);
        }
    }
}

extern "C" void kernel_launch(void* const* d_in, const int* in_sizes, int n_in,
                              void* d_out, int out_size, void* d_ws, size_t ws_size,
                              hipStream_t stream) {
    const float* user_embed = (const float*)d_in[0];
    const float* item_embed = (const float*)d_in[1];
    const float* Wq = (const float*)d_in[2];
    const float* Wk = (const float*)d_in[3];
    const float* Wv = (const float*)d_in[4];
    const float* ent_real = (const float*)d_in[5];
    const float* ent_imag = (const float*)d_in[6];
    const float* rel_real = (const float*)d_in[7];
    const float* rel_imag = (const float*)d_in[8];
    const float* fp_W1 = (const float*)d_in[9];
    const float* fp_b1 = (const float*)d_in[10];
    const float* fp_W2 = (const float*)d_in[11];
    const float* fp_b2 = (const float*)d_in[12];
    const float* rt_W1 = (const float*)d_in[13];
    const float* rt_b1 = (const float*)d_in[14];
    const float* rt_W2 = (const float*)d_in[15];
    const float* rt_b2 = (const float*)d_in[16];
    const float* relation_emb = (const float*)d_in[17];
    const float* user_emb = (const float*)d_in[18];
    const float* entity_emb = (const float*)d_in[19];
    const float* inter_edge_w = (const float*)d_in[20];
    const int* edge_index = (const int*)d_in[21];
    const int* edge_type = (const int*)d_in[22];
    const int* inter_edge = (const int*)d_in[23];
    float* out = (float*)d_out;

    float* W = (float*)d_ws;
    size_t off = 0;
    auto alloc = [&](size_t n) { float* r = W + off; off += n; return r; };
    // persistent floats
    float* omg    = alloc(NE);
    float* w0a    = alloc(NE);
    float* w1a    = alloc(NE);
    float* w2a    = alloc(NE);
    float* exA    = alloc(NEI);
    float* csr_a  = alloc(NE);
    float* csr_et = alloc(NE);
    float* c      = alloc(N_ITEMS);   // c and p adjacent -> single memset
    float* p      = alloc(64);
    float* v2     = alloc(64);
    float* cb     = alloc(64);
    float* RR1    = alloc(10 * D);
    float* PSI    = alloc(10 * D);
    // persistent ints (region starts 8B-aligned: float count so far is even)
    int* IW = (int*)(W + off);
    size_t ioff = 0;
    auto ialloc = [&](size_t n) { int* r = IW + ioff; ioff += n; return r; };
    int2* csr_itw = (int2*)ialloc(2 * NEI);   // packed (item, wbits)
    int* csr_tr = ialloc(NE);
    int* cntU   = ialloc(N_USERS);            // cntU/cntH adjacent -> single memset
    int* cntH   = ialloc(N_ENT);
    int* offU   = ialloc(N_USERS + 1);
    int* curU   = ialloc(N_USERS);
    int* offH   = ialloc(N_ENT + 1);
    int* curH   = ialloc(N_ENT);
    int* bsumU  = ialloc(256);
    int* bsxU   = ialloc(257);
    int* bsumH  = ialloc(256);
    int* bsxH   = ialloc(257);
    off += ioff;
    // union region
    float* U = W + off;
    // phase A (within EH slot)
    bf16*  IkB = (bf16*)U;
    float* Iv  = U + (size_t)N_ITEMS * 32;
    float* Uq  = Iv + (size_t)N_ITEMS * D;
    // phase B
    float* EH  = U;
    float* ET  = EH + (size_t)N_ENT * D;
    float* PHI = U;                             // overwrites EH after omega1
    // phase C: eA over dead ET slot, eB over dead PHI slot
    bf16* eA = (bf16*)ET;
    bf16* eB = (bf16*)U;

    const int nbU = (N_USERS + 1023) / 1024;    // 49
    const int nbH = (N_ENT + 1023) / 1024;      // 98
    const int s3U = (N_USERS + 256) / 256;      // blocks covering N_USERS+1
    const int s3H = (N_ENT + 256) / 256;
    const int IB = (N_ITEMS + 63) / 64;
    const int UB = (N_USERS + 63) / 64;
    const int EB = (N_ENT + 63) / 64;
    const int OB = (N_ENT + 3) / 4;             // omega wave-blocks
    const int CB = (N_ENT * D) / 1024;          // cvt blocks (exact)
    const int HE = (N_ENT + 3) / 4;
    const int HU = (N_USERS + 3) / 4;

    // ---- CSR build ----
    hipMemsetAsync(cntU, 0, (N_USERS + N_ENT) * 4, stream);
    hipMemsetAsync(c, 0, (N_ITEMS + 64) * 4, stream);
    k_hist2<<<(NEI + NE + 255) / 256, 256, 0, stream>>>(inter_edge, edge_index, cntU, cntH);
    k_scan1<<<nbU + nbH, 256, 0, stream>>>(cntU, offU, bsumU, N_USERS, nbU,
                                           cntH, offH, bsumH, N_ENT);
    k_scan2<<<2, 256, 0, stream>>>(bsumU, bsxU, nbU, bsumH, bsxH, nbH);
    k_scan3<<<s3U + s3H, 256, 0, stream>>>(offU, curU, bsxU, N_USERS, nbU, s3U,
                                           offH, curH, bsxH, N_ENT, nbH);
    k_scatter<<<(NEI + NE + 255) / 256, 256, 0, stream>>>(inter_edge, inter_edge_w,
                                                          edge_index, edge_type,
                                                          curU, curH, csr_itw, csr_tr);

    // ---- Phase A ----
    k_proj<<<IB + UB, 256, 0, stream>>>(item_embed, Wk, Wv, user_embed, Wq,
                                        IkB, Iv, Uq, IB);
    k_userAB<<<(N_USERS + 3) / 4, 256, 0, stream>>>(offU, csr_itw, Uq, IkB, exA, c, N_USERS);
    k_pdense<<<64, 256, 0, stream>>>(c, Iv, p, N_ITEMS);

    // ---- Phase B ----
    k_entabx<<<EB + 2, 256, 0, stream>>>(ent_real, ent_imag, fp_W1, rel_real, rel_imag,
                                         rt_W1, rt_W2, rt_b2, p, EH, ET, RR1, PSI,
                                         v2, cb, EB);
    k_omega1<<<(N_ENT + 3) / 4, 256, 0, stream>>>(offH, csr_tr, EH, ET, RR1, fp_b1,
                                                  fp_W2, fp_b2, w0a, w1a, w2a, N_ENT);
    k_ent_phi<<<EB, 256, 0, stream>>>(ent_real, ent_imag, rt_W1, PHI, N_ENT);
    k_omega2cvt<<<OB + CB, 256, 0, stream>>>(offH, csr_tr, PHI, PSI, rt_b1, v2, cb,
                                             w0a, w1a, w2a, omg, csr_a, csr_et,
                                             entity_emb, eA, OB, N_ENT);

    // ---- hops ----
    bf16* ecur = eA;
    bf16* enxt = eB;
    for (int hop = 1; hop <= 3; hop++) {
        const float* rho = (hop < 3) ? csr_a : csr_et;
        int init = (hop == 1) ? 1 : 0;
        k_hop<<<HE + HU, 256, 0, stream>>>(offH, csr_tr, rho, relation_emb,
                                           offU, csr_itw, ecur, enxt,
                                           entity_emb, user_emb,
                                           out, out + (size_t)N_ENT * D, init, HE);
        bf16* tmp = ecur; ecur = enxt; enxt = tmp;
    }
}

// Round 7
// 940.006 us; speedup vs baseline: 4.6130x; 4.6130x over previous
//
#include <hip/hip_runtime.h>
#include <hip/hip_bf16.h>
#include <math.h>

#define N_USERS 50000
#define N_ITEMS 30000
#define N_ENT   100000
#define NE      500000      // KG edges E
#define NEI     1000000     // interaction edges EI
#define D       64
#define GAMMA   0.2f

typedef __hip_bfloat16 bf16;

__device__ __forceinline__ float wave_sum(float v) {
    #pragma unroll
    for (int off = 32; off > 0; off >>= 1) v += __shfl_xor(v, off, 64);
    return v;
}

__device__ __forceinline__ float g16_sum(float v) {
    #pragma unroll
    for (int off = 1; off < 16; off <<= 1) v += __shfl_xor(v, off, 64);
    return v;
}

__device__ __forceinline__ float bits2f(unsigned short u) {
    return __uint_as_float(((unsigned)u) << 16);
}

__device__ __forceinline__ unsigned short f2bf_bits(float f) {
    bf16 b = __float2bfloat16(f);
    return *(unsigned short*)&b;
}

__device__ __forceinline__ float sigmoidf(float x) { return 1.0f / (1.0f + expf(-x)); }

__device__ __forceinline__ float n2n(float y) {
    if (isnan(y)) return 0.0f;
    if (isinf(y)) return y > 0.0f ? 1e4f : 1e-4f;
    return y;
}

// ================= CSR build (fused U+H) =================
__global__ void k_hist2(const int* __restrict__ ie, const int* __restrict__ eidx,
                        int* __restrict__ cntU, int* __restrict__ cntH) {
    int e = blockIdx.x * blockDim.x + threadIdx.x;
    if (e < NEI) atomicAdd(&cntU[ie[e]], 1);
    else if (e < NEI + NE) atomicAdd(&cntH[eidx[e - NEI]], 1);
}

__global__ void k_scan1(const int* __restrict__ cntU_, int* __restrict__ offU_,
                        int* __restrict__ bsumU_, int nU, int nbU,
                        const int* __restrict__ cntH_, int* __restrict__ offH_,
                        int* __restrict__ bsumH_, int nH) {
    __shared__ int sh[256];
    int t = threadIdx.x;
    int b = blockIdx.x;
    const int* cnt; int* off; int* bsum; int n; int lb;
    if (b < nbU) { cnt = cntU_; off = offU_; bsum = bsumU_; n = nU; lb = b; }
    else         { cnt = cntH_; off = offH_; bsum = bsumH_; n = nH; lb = b - nbU; }
    int base = lb * 1024 + t * 4;
    int v[4];
    #pragma unroll
    for (int j = 0; j < 4; j++) v[j] = (base + j < n) ? cnt[base + j] : 0;
    int tot = v[0] + v[1] + v[2] + v[3];
    sh[t] = tot;
    __syncthreads();
    for (int d = 1; d < 256; d <<= 1) {
        int x = (t >= d) ? sh[t - d] : 0;
        __syncthreads();
        sh[t] += x;
        __syncthreads();
    }
    int run = sh[t] - tot;
    #pragma unroll
    for (int j = 0; j < 4; j++) {
        if (base + j < n) off[base + j] = run;
        run += v[j];
    }
    if (t == 255) bsum[lb] = sh[255];
}

__global__ void k_scan2(const int* __restrict__ bsumU_, int* __restrict__ bsxU_, int nbU,
                        const int* __restrict__ bsumH_, int* __restrict__ bsxH_, int nbH) {
    __shared__ int sh[256];
    int t = threadIdx.x;
    const int* bsum; int* bsx; int nb;
    if (blockIdx.x == 0) { bsum = bsumU_; bsx = bsxU_; nb = nbU; }
    else                 { bsum = bsumH_; bsx = bsxH_; nb = nbH; }
    int v = (t < nb) ? bsum[t] : 0;
    sh[t] = v;
    __syncthreads();
    for (int d = 1; d < 256; d <<= 1) {
        int x = (t >= d) ? sh[t - d] : 0;
        __syncthreads();
        sh[t] += x;
        __syncthreads();
    }
    if (t < nb) bsx[t] = sh[t] - v;
    if (t == 255) bsx[nb] = sh[255];
}

__global__ void k_scan3(int* __restrict__ offU_, int* __restrict__ curU_,
                        const int* __restrict__ bsxU_, int nU, int nbU, int blocksU,
                        int* __restrict__ offH_, int* __restrict__ curH_,
                        const int* __restrict__ bsxH_, int nH, int nbH) {
    int b = blockIdx.x;
    int* off; int* cur; const int* bsx; int n; int nb; int i;
    if (b < blocksU) { off = offU_; cur = curU_; bsx = bsxU_; n = nU; nb = nbU; i = b * 256 + threadIdx.x; }
    else             { off = offH_; cur = curH_; bsx = bsxH_; n = nH; nb = nbH; i = (b - blocksU) * 256 + threadIdx.x; }
    if (i > n) return;
    int val = (i == n) ? bsx[nb] : off[i] + bsx[i >> 10];
    off[i] = val;
    if (i < n) cur[i] = val;
}

__global__ void k_scatter(const int* __restrict__ ie, const float* __restrict__ w,
                          const int* __restrict__ eidx, const int* __restrict__ etype,
                          int* __restrict__ curU, int* __restrict__ curH,
                          int2* __restrict__ itw, int* __restrict__ csr_tr) {
    int e = blockIdx.x * blockDim.x + threadIdx.x;
    if (e < NEI) {
        int u = ie[e];
        int pos = atomicAdd(&curU[u], 1);
        itw[pos] = make_int2(ie[NEI + e], __float_as_int(w[e]));
    } else if (e < NEI + NE) {
        int e2 = e - NEI;
        int h = eidx[e2];
        int pos = atomicAdd(&curH[h], 1);
        csr_tr[pos] = eidx[NE + e2] | ((etype[e2] - 1) << 20);
    }
}

// ================= lane-owns-row tiled GEMM helpers =================
__device__ __forceinline__ void stage_rows2(const float* __restrict__ s0,
                                            const float* __restrict__ s1,
                                            float* At, int row0, int n, int t) {
    #pragma unroll
    for (int half = 0; half < 2; half++) {
        const float* src = half ? s1 : s0;
        int kofs = half ? 32 : 0;
        #pragma unroll
        for (int fi = t, it = 0; it < 2; fi += 256, it++) {
            int row = fi >> 3;
            int k4 = (fi & 7) << 2;
            float4 v = make_float4(0.f, 0.f, 0.f, 0.f);
            if (row0 + row < n) v = *(const float4*)&src[(size_t)(row0 + row) * 32 + k4];
            At[(kofs + k4 + 0) * 64 + row] = v.x;
            At[(kofs + k4 + 1) * 64 + row] = v.y;
            At[(kofs + k4 + 2) * 64 + row] = v.z;
            At[(kofs + k4 + 3) * 64 + row] = v.w;
        }
    }
}

__device__ __forceinline__ void stage_rows1(const float* __restrict__ src,
                                            float* At, int row0, int n, int t) {
    #pragma unroll
    for (int fi = t, it = 0; it < 4; fi += 256, it++) {
        int row = fi >> 4;
        int k4 = (fi & 15) << 2;
        float4 v = make_float4(0.f, 0.f, 0.f, 0.f);
        if (row0 + row < n) v = *(const float4*)&src[(size_t)(row0 + row) * 64 + k4];
        At[(k4 + 0) * 64 + row] = v.x;
        At[(k4 + 1) * 64 + row] = v.y;
        At[(k4 + 2) * 64 + row] = v.z;
        At[(k4 + 3) * 64 + row] = v.w;
    }
}

// fused: blocks [0,IB) item proj (Ik bf16 + Iv), [IB, IB+UB) user proj (Uq)
__global__ __launch_bounds__(256) void k_proj(const float* __restrict__ I,
        const float* __restrict__ Wk, const float* __restrict__ Wv,
        const float* __restrict__ UE, const float* __restrict__ Wq,
        bf16* __restrict__ IkB, float* __restrict__ Iv, float* __restrict__ Uq, int IB) {
    __shared__ float At[64 * 64];
    int t = threadIdx.x;
    int b = blockIdx.x;
    int lane = t & 63;
    int wv = __builtin_amdgcn_readfirstlane(t >> 6);
    if (b < IB) {
        int row0 = b << 6;
        stage_rows1(I, At, row0, N_ITEMS, t);
        __syncthreads();
        const float* Wb = ((wv >> 1) ? Wv : Wk) + (wv & 1) * 32;
        float acc[32];
        #pragma unroll
        for (int c = 0; c < 32; c++) acc[c] = 0.f;
        for (int k = 0; k < 64; k++) {
            float a = At[k * 64 + lane];
            const float* wr = Wb + k * 64;
            #pragma unroll
            for (int c4 = 0; c4 < 8; c4++) {
                float4 w4 = *(const float4*)&wr[c4 * 4];
                acc[c4 * 4 + 0] += a * w4.x;
                acc[c4 * 4 + 1] += a * w4.y;
                acc[c4 * 4 + 2] += a * w4.z;
                acc[c4 * 4 + 3] += a * w4.w;
            }
        }
        int row = row0 + lane;
        if (row < N_ITEMS) {
            if (wv >> 1) {
                float* dst = Iv + (size_t)row * 64 + (wv & 1) * 32;
                #pragma unroll
                for (int c4 = 0; c4 < 8; c4++)
                    *(float4*)&dst[c4 * 4] = make_float4(acc[c4*4], acc[c4*4+1], acc[c4*4+2], acc[c4*4+3]);
            } else {
                bf16* dst = IkB + (size_t)row * 64 + (wv & 1) * 32;
                #pragma unroll
                for (int c4 = 0; c4 < 8; c4++) {
                    ushort4 s;
                    s.x = f2bf_bits(acc[c4 * 4 + 0]);
                    s.y = f2bf_bits(acc[c4 * 4 + 1]);
                    s.z = f2bf_bits(acc[c4 * 4 + 2]);
                    s.w = f2bf_bits(acc[c4 * 4 + 3]);
                    *(ushort4*)&dst[c4 * 4] = s;
                }
            }
        }
    } else {
        int row0 = (b - IB) << 6;
        stage_rows1(UE, At, row0, N_USERS, t);
        __syncthreads();
        const float* Wb = Wq + wv * 16;
        float acc[16];
        #pragma unroll
        for (int c = 0; c < 16; c++) acc[c] = 0.f;
        for (int k = 0; k < 64; k++) {
            float a = At[k * 64 + lane];
            const float* wr = Wb + k * 64;
            #pragma unroll
            for (int c4 = 0; c4 < 4; c4++) {
                float4 w4 = *(const float4*)&wr[c4 * 4];
                acc[c4 * 4 + 0] += a * w4.x;
                acc[c4 * 4 + 1] += a * w4.y;
                acc[c4 * 4 + 2] += a * w4.z;
                acc[c4 * 4 + 3] += a * w4.w;
            }
        }
        int row = row0 + lane;
        if (row < N_USERS) {
            float* dst = Uq + (size_t)row * 64 + wv * 16;
            #pragma unroll
            for (int c4 = 0; c4 < 4; c4++)
                *(float4*)&dst[c4 * 4] = make_float4(acc[c4*4], acc[c4*4+1], acc[c4*4+2], acc[c4*4+3]);
        }
    }
}

// ================= Stage A edge kernels (two dispatches — NO fences) =================
__global__ void k_userA(const int* __restrict__ offU, const int2* __restrict__ itw,
                        const float* __restrict__ Uq, const bf16* __restrict__ IkB,
                        float* __restrict__ exA, float* __restrict__ denU, int n) {
    int u = (blockIdx.x * blockDim.x + threadIdx.x) >> 6;
    int lane = threadIdx.x & 63;
    if (u >= n) return;
    int s = offU[u], e = offU[u + 1];
    if (s == e) return;
    int l = lane & 15, g = lane >> 4;
    float4 qv = *(const float4*)&Uq[(size_t)u * D + l * 4];
    float den = 0.f;
    for (int j0 = s; j0 < e; j0 += 4) {
        int j = j0 + g;
        bool valid = j < e;
        int jj = valid ? j : s;
        int2 iw = itw[jj];
        ushort4 ik = *(const ushort4*)&IkB[(size_t)iw.x * D + l * 4];
        float d = qv.x * bits2f(ik.x) + qv.y * bits2f(ik.y) +
                  qv.z * bits2f(ik.z) + qv.w * bits2f(ik.w);
        float sc = g16_sum(d);
        float ex = valid ? expf(sc * 0.125f * __int_as_float(iw.y)) : 0.f;
        den += ex;
        if (valid && l == 0) exA[j] = ex;
    }
    den += __shfl_xor(den, 16, 64);
    den += __shfl_xor(den, 32, 64);
    if (lane == 0) denU[u] = den * (float)(e - s);  // den * deg
}

__global__ void k_userB(const int* __restrict__ offU, const int2* __restrict__ itw,
                        const float* __restrict__ exA, const float* __restrict__ denU,
                        float* __restrict__ c, int n) {
    int u = (blockIdx.x * blockDim.x + threadIdx.x) >> 6;
    int lane = threadIdx.x & 63;
    if (u >= n) return;
    int s = offU[u], e = offU[u + 1];
    if (s == e) return;
    float inv = 1.0f / denU[u];
    for (int j = s + lane; j < e; j += 64)
        atomicAdd(&c[itw[j].x], exA[j] * inv);
}

__global__ void k_pdense(const float* __restrict__ c, const float* __restrict__ Iv,
                         float* __restrict__ p, int n) {
    int lane = threadIdx.x & 63;
    int gw = blockIdx.x * 4 + (threadIdx.x >> 6);
    int nw = gridDim.x * 4;
    float acc = 0.f;
    for (int i = gw; i < n; i += nw) acc += c[i] * Iv[(size_t)i * D + lane];
    __shared__ float red[256];
    red[threadIdx.x] = acc;
    __syncthreads();
    if (threadIdx.x < 64) {
        float s = red[threadIdx.x] + red[threadIdx.x + 64] + red[threadIdx.x + 128] + red[threadIdx.x + 192];
        atomicAdd(&p[threadIdx.x], s);
    }
}

// ================= Stage B: ent_ab + rel_tables + v2 in one dispatch =================
__global__ __launch_bounds__(256) void k_entabx(const float* __restrict__ er,
        const float* __restrict__ ei, const float* __restrict__ fpW1,
        const float* __restrict__ rr, const float* __restrict__ ri,
        const float* __restrict__ rtW1, const float* __restrict__ rtW2,
        const float* __restrict__ rt_b2, const float* __restrict__ p,
        float* __restrict__ EH, float* __restrict__ ET,
        float* __restrict__ RR1, float* __restrict__ PSI,
        float* __restrict__ v2, float* __restrict__ cb, int EB) {
    __shared__ float At[64 * 64];
    int b = blockIdx.x;
    int t = threadIdx.x;
    if (b < EB) {
        int row0 = b << 6;
        stage_rows2(er, ei, At, row0, N_ENT, t);
        __syncthreads();
        int lane = t & 63;
        int wv = __builtin_amdgcn_readfirstlane(t >> 6);
        const float* Wb = fpW1 + ((wv >> 1) ? (128 * 64) : 0) + (wv & 1) * 32;
        float acc[32];
        #pragma unroll
        for (int c = 0; c < 32; c++) acc[c] = 0.f;
        for (int k = 0; k < 64; k++) {
            float a = At[k * 64 + lane];
            const float* wr = Wb + k * 64;
            #pragma unroll
            for (int c4 = 0; c4 < 8; c4++) {
                float4 w4 = *(const float4*)&wr[c4 * 4];
                acc[c4 * 4 + 0] += a * w4.x;
                acc[c4 * 4 + 1] += a * w4.y;
                acc[c4 * 4 + 2] += a * w4.z;
                acc[c4 * 4 + 3] += a * w4.w;
            }
        }
        int row = row0 + lane;
        if (row < N_ENT) {
            float* dst = ((wv >> 1) ? ET : EH) + (size_t)row * 64 + (wv & 1) * 32;
            #pragma unroll
            for (int c4 = 0; c4 < 8; c4++)
                *(float4*)&dst[c4 * 4] = make_float4(acc[c4*4], acc[c4*4+1], acc[c4*4+2], acc[c4*4+3]);
        }
    } else if (b == EB) {
        if (t < 64) {
            int lane = t;
            for (int r = 0; r < 10; r++) {
                float a = 0.f, bb = 0.f;
                for (int k = 0; k < 32; k++) {
                    float sr = rr[r * 32 + k], si = ri[r * 32 + k];
                    a  += sr * fpW1[(64 + k) * D + lane] + si * fpW1[(96 + k) * D + lane];
                    bb += sr * rtW1[k * D + lane] + si * rtW1[(32 + k) * D + lane];
                }
                RR1[r * D + lane] = a;
                PSI[r * D + lane] = bb;
            }
        }
    } else {
        if (t < 64) {
            int j = t;
            float acc = 0.f;
            #pragma unroll
            for (int k = 0; k < D; k++) acc += rtW2[j * D + k] * p[k];
            v2[j] = acc;
            float cc = rt_b2[j] * p[j];
            cc = wave_sum(cc);
            if (j == 0) cb[0] = cc;
        }
    }
}

// PHI = [er|ei]@rtW1
__global__ __launch_bounds__(256) void k_ent_phi(const float* __restrict__ er,
        const float* __restrict__ ei, const float* __restrict__ rtW1,
        float* __restrict__ PHI, int n) {
    __shared__ float At[64 * 64];
    int t = threadIdx.x;
    int row0 = blockIdx.x << 6;
    stage_rows2(er, ei, At, row0, n, t);
    __syncthreads();
    int lane = t & 63;
    int wv = __builtin_amdgcn_readfirstlane(t >> 6);
    const float* Wb = rtW1 + wv * 16;
    float acc[16];
    #pragma unroll
    for (int c = 0; c < 16; c++) acc[c] = 0.f;
    for (int k = 0; k < 64; k++) {
        float a = At[k * 64 + lane];
        const float* wr = Wb + k * 64;
        #pragma unroll
        for (int c4 = 0; c4 < 4; c4++) {
            float4 w4 = *(const float4*)&wr[c4 * 4];
            acc[c4 * 4 + 0] += a * w4.x;
            acc[c4 * 4 + 1] += a * w4.y;
            acc[c4 * 4 + 2] += a * w4.z;
            acc[c4 * 4 + 3] += a * w4.w;
        }
    }
    int row = row0 + lane;
    if (row < n) {
        float* dst = PHI + (size_t)row * 64 + wv * 16;
        #pragma unroll
        for (int c4 = 0; c4 < 4; c4++)
            *(float4*)&dst[c4 * 4] = make_float4(acc[c4*4], acc[c4*4+1], acc[c4*4+2], acc[c4*4+3]);
    }
}

// wave/head, 16-lane subgroups, 4 edges in flight: gate weights
__global__ void k_omega1(const int* __restrict__ offH, const int* __restrict__ csr_tr,
                         const float* __restrict__ EH, const float* __restrict__ ET,
                         const float* __restrict__ RR1, const float* __restrict__ fp_b1,
                         const float* __restrict__ fpW2, const float* __restrict__ fp_b2,
                         float* __restrict__ w0a, float* __restrict__ w1a,
                         float* __restrict__ w2a, int n) {
    int h = (blockIdx.x * blockDim.x + threadIdx.x) >> 6;
    int lane = threadIdx.x & 63;
    if (h >= n) return;
    int s = offH[h], e = offH[h + 1];
    if (s == e) return;
    int l = lane & 15, g = lane >> 4;
    int d0 = l * 4;
    float4 ehh = *(const float4*)&EH[(size_t)h * D + d0];
    float4 b1 = *(const float4*)&fp_b1[d0];
    ehh.x += b1.x; ehh.y += b1.y; ehh.z += b1.z; ehh.w += b1.w;
    float f0[4], f1[4], f2[4];
    #pragma unroll
    for (int cc = 0; cc < 4; cc++) {
        f0[cc] = fpW2[(d0 + cc) * 3 + 0];
        f1[cc] = fpW2[(d0 + cc) * 3 + 1];
        f2[cc] = fpW2[(d0 + cc) * 3 + 2];
    }
    float b20 = fp_b2[0], b21 = fp_b2[1], b22 = fp_b2[2];
    for (int j0 = s; j0 < e; j0 += 4) {
        int j = j0 + g;
        bool valid = j < e;
        int jj = valid ? j : s;
        int pk = csr_tr[jj];
        int t = pk & 0xFFFFF, r = pk >> 20;
        float4 et = *(const float4*)&ET[(size_t)t * D + d0];
        float4 rr = *(const float4*)&RR1[r * D + d0];
        float z0 = sigmoidf(ehh.x + rr.x + et.x);
        float z1 = sigmoidf(ehh.y + rr.y + et.y);
        float z2 = sigmoidf(ehh.z + rr.z + et.z);
        float z3 = sigmoidf(ehh.w + rr.w + et.w);
        float a0 = z0 * f0[0] + z1 * f0[1] + z2 * f0[2] + z3 * f0[3];
        float a1 = z0 * f1[0] + z1 * f1[1] + z2 * f1[2] + z3 * f1[3];
        float a2 = z0 * f2[0] + z1 * f2[1] + z2 * f2[2] + z3 * f2[3];
        a0 = g16_sum(a0); a1 = g16_sum(a1); a2 = g16_sum(a2);
        if (valid && l == 0) {
            a0 += b20; a1 += b21; a2 += b22;
            float mx = fmaxf(a0, fmaxf(a1, a2));
            float e0 = expf(a0 - mx), e1 = expf(a1 - mx), e2 = expf(a2 - mx);
            float inv = 1.0f / (e0 + e1 + e2);
            w0a[j] = e0 * inv;
            w1a[j] = e1 * inv;
            w2a[j] = e2 * inv;
        }
    }
}

// omega + segO (wave-local) with cvt blocks appended; NO fence
__global__ void k_omega2a(const int* __restrict__ offH, const int* __restrict__ csr_tr,
                          const float* __restrict__ PHI, const float* __restrict__ PSI,
                          const float* __restrict__ rt_b1, const float* __restrict__ v2,
                          const float* __restrict__ cb, const float* __restrict__ w0a,
                          const float* __restrict__ w1a, const float* __restrict__ w2a,
                          float* __restrict__ omg, float* __restrict__ segO,
                          const float* __restrict__ src_emb, bf16* __restrict__ eA,
                          int OB, int n) {
    int b = blockIdx.x;
    if (b >= OB) {
        int base = (b - OB) * 1024 + threadIdx.x * 4;
        float4 v = *(const float4*)&src_emb[base];
        ushort4 s;
        s.x = f2bf_bits(v.x); s.y = f2bf_bits(v.y);
        s.z = f2bf_bits(v.z); s.w = f2bf_bits(v.w);
        *(ushort4*)&eA[base] = s;
        return;
    }
    int h = (b * blockDim.x + threadIdx.x) >> 6;
    int lane = threadIdx.x & 63;
    if (h >= n) return;
    int s = offH[h], e = offH[h + 1];
    if (s == e) return;
    int l = lane & 15, g = lane >> 4;
    int d0 = l * 4;
    float4 phh = *(const float4*)&PHI[(size_t)h * D + d0];
    float4 rb = *(const float4*)&rt_b1[d0];
    float4 vv = *(const float4*)&v2[d0];
    float cc = cb[0];
    float so = 0.f;
    for (int j0 = s; j0 < e; j0 += 4) {
        int j = j0 + g;
        bool valid = j < e;
        int jj = valid ? j : s;
        int pk = csr_tr[jj];
        int t = pk & 0xFFFFF, r = pk >> 20;
        float W0 = w0a[jj], W1 = w1a[jj], W2 = w2a[jj];
        float4 pt = *(const float4*)&PHI[(size_t)t * D + d0];
        float4 ps = *(const float4*)&PSI[r * D + d0];
        float sv = sigmoidf(W0 * phh.x + W1 * ps.x + W2 * pt.x + rb.x) * vv.x
                 + sigmoidf(W0 * phh.y + W1 * ps.y + W2 * pt.y + rb.y) * vv.y
                 + sigmoidf(W0 * phh.z + W1 * ps.z + W2 * pt.z + rb.z) * vv.z
                 + sigmoidf(W0 * phh.w + W1 * ps.w + W2 * pt.w + rb.w) * vv.w;
        sv = g16_sum(sv);
        float om = (sv + cc) * 0.125f;
        if (valid) {
            if (l == 0) omg[j] = om;
            so += om;
        }
    }
    so += __shfl_xor(so, 16, 64);
    so += __shfl_xor(so, 32, 64);
    if (lane == 0) segO[h] = so;
}

// alpha + eta from stored omg/segO (separate dispatch = visibility boundary)
__global__ void k_omega2b(const int* __restrict__ offH, const float* __restrict__ omg,
                          const float* __restrict__ segO, float* __restrict__ csr_a,
                          float* __restrict__ csr_et, int n) {
    int h = (blockIdx.x * blockDim.x + threadIdx.x) >> 6;
    int lane = threadIdx.x & 63;
    if (h >= n) return;
    int s = offH[h], e = offH[h + 1];
    if (s == e) return;
    float invO = 1.0f / (segO[h] + 1e-8f);
    float se = 0.f;
    for (int j = s + lane; j < e; j += 64) {
        float a = omg[j] * invO;
        csr_a[j] = a;
        se += (a > GAMMA) ? a : 0.0f;
    }
    se = wave_sum(se);
    float invE = 1.0f / (se + 1e-8f);
    for (int j = s + lane; j < e; j += 64) {
        float a = csr_a[j];
        csr_et[j] = ((a > GAMMA) ? a : 0.0f) * invE;
    }
}

// ================= fused hop: blocks [0,EB) entity side, rest user side =================
__global__ void k_hop(const int* __restrict__ offH, const int* __restrict__ tr,
                      const float* __restrict__ rho, const float* __restrict__ rel,
                      const int* __restrict__ offU, const int2* __restrict__ itw,
                      const bf16* __restrict__ ecur, bf16* __restrict__ enxt,
                      const float* __restrict__ initE, const float* __restrict__ initU,
                      float* __restrict__ outE, float* __restrict__ outU,
                      int init, int EB) {
    int b = blockIdx.x;
    int lane = threadIdx.x & 63;
    int l = lane & 15, g = lane >> 4;
    int d0 = l * 4;
    if (b < EB) {
        int gw = b * 4 + (threadIdx.x >> 6);
        if (gw >= N_ENT) return;
        int s = offH[gw], e = offH[gw + 1];
        float a0 = 0.f, a1 = 0.f, a2 = 0.f, a3 = 0.f;
        for (int j0 = s; j0 < e; j0 += 4) {
            int j = j0 + g;
            bool valid = j < e;
            int jj = valid ? j : s;
            int pk = tr[jj];
            int t = pk & 0xFFFFF, r = pk >> 20;
            float rh = valid ? rho[jj] : 0.f;
            ushort4 ev = *(const ushort4*)&ecur[(size_t)t * D + d0];
            float4 rl = *(const float4*)&rel[r * D + d0];
            a0 += rh * bits2f(ev.x) * rl.x;
            a1 += rh * bits2f(ev.y) * rl.y;
            a2 += rh * bits2f(ev.z) * rl.z;
            a3 += rh * bits2f(ev.w) * rl.w;
        }
        a0 += __shfl_xor(a0, 16, 64); a0 += __shfl_xor(a0, 32, 64);
        a1 += __shfl_xor(a1, 16, 64); a1 += __shfl_xor(a1, 32, 64);
        a2 += __shfl_xor(a2, 16, 64); a2 += __shfl_xor(a2, 32, 64);
        a3 += __shfl_xor(a3, 16, 64); a3 += __shfl_xor(a3, 32, 64);
        float invd = 1.0f / fmaxf((float)(e - s), 1.0f);
        a0 *= invd; a1 *= invd; a2 *= invd; a3 *= invd;
        float ss = a0 * a0 + a1 * a1 + a2 * a2 + a3 * a3;
        ss = g16_sum(ss);
        float nrm = fmaxf(sqrtf(ss), 1e-8f);
        float y0 = n2n(a0 / nrm), y1 = n2n(a1 / nrm), y2 = n2n(a2 / nrm), y3 = n2n(a3 / nrm);
        if (g == 0) {
            ushort4 st;
            st.x = f2bf_bits(y0); st.y = f2bf_bits(y1); st.z = f2bf_bits(y2); st.w = f2bf_bits(y3);
            *(ushort4*)&enxt[(size_t)gw * D + d0] = st;
            size_t o = (size_t)gw * D + d0;
            float4 prev;
            if (init) prev = *(const float4*)&initE[o];
            else      prev = *(const float4*)&outE[o];
            *(float4*)&outE[o] = make_float4(prev.x + y0, prev.y + y1, prev.z + y2, prev.w + y3);
        }
    } else {
        int gw = (b - EB) * 4 + (threadIdx.x >> 6);
        if (gw >= N_USERS) return;
        int s = offU[gw], e = offU[gw + 1];
        float a0 = 0.f, a1 = 0.f, a2 = 0.f, a3 = 0.f;
        for (int j0 = s; j0 < e; j0 += 4) {
            int j = j0 + g;
            bool valid = j < e;
            int jj = valid ? j : s;
            int2 iw = itw[jj];
            float w = valid ? __int_as_float(iw.y) : 0.f;
            ushort4 ev = *(const ushort4*)&ecur[(size_t)iw.x * D + d0];
            a0 += w * bits2f(ev.x);
            a1 += w * bits2f(ev.y);
            a2 += w * bits2f(ev.z);
            a3 += w * bits2f(ev.w);
        }
        a0 += __shfl_xor(a0, 16, 64); a0 += __shfl_xor(a0, 32, 64);
        a1 += __shfl_xor(a1, 16, 64); a1 += __shfl_xor(a1, 32, 64);
        a2 += __shfl_xor(a2, 16, 64); a2 += __shfl_xor(a2, 32, 64);
        a3 += __shfl_xor(a3, 16, 64); a3 += __shfl_xor(a3, 32, 64);
        float ss = a0 * a0 + a1 * a1 + a2 * a2 + a3 * a3;
        ss = g16_sum(ss);
        float nrm = fmaxf(sqrtf(ss), 1e-8f);
        float y0 = n2n(a0 / nrm), y1 = n2n(a1 / nrm), y2 = n2n(a2 / nrm), y3 = n2n(a3 / nrm);
        if (g == 0) {
            size_t o = (size_t)gw * D + d0;
            float4 prev;
            if (init) prev = *(const float4*)&initU[o];
            else      prev = *(const float4*)&outU[o];
            *(float4*)&outU[o] = make_float4(prev.x + y0, prev.y + y1, prev.z + y2, prev.w + y3);
        }
    }
}

extern "C" void kernel_launch(void* const* d_in, const int* in_sizes, int n_in,
                              void* d_out, int out_size, void* d_ws, size_t ws_size,
                              hipStream_t stream) {
    const float* user_embed = (const float*)d_in[0];
    const float* item_embed = (const float*)d_in[1];
    const float* Wq = (const float*)d_in[2];
    const float* Wk = (const float*)d_in[3];
    const float* Wv = (const float*)d_in[4];
    const float* ent_real = (const float*)d_in[5];
    const float* ent_imag = (const float*)d_in[6];
    const float* rel_real = (const float*)d_in[7];
    const float* rel_imag = (const float*)d_in[8];
    const float* fp_W1 = (const float*)d_in[9];
    const float* fp_b1 = (const float*)d_in[10];
    const float* fp_W2 = (const float*)d_in[11];
    const float* fp_b2 = (const float*)d_in[12];
    const float* rt_W1 = (const float*)d_in[13];
    const float* rt_b1 = (const float*)d_in[14];
    const float* rt_W2 = (const float*)d_in[15];
    const float* rt_b2 = (const float*)d_in[16];
    const float* relation_emb = (const float*)d_in[17];
    const float* user_emb = (const float*)d_in[18];
    const float* entity_emb = (const float*)d_in[19];
    const float* inter_edge_w = (const float*)d_in[20];
    const int* edge_index = (const int*)d_in[21];
    const int* edge_type = (const int*)d_in[22];
    const int* inter_edge = (const int*)d_in[23];
    float* out = (float*)d_out;

    float* W = (float*)d_ws;
    size_t off = 0;
    auto alloc = [&](size_t n) { float* r = W + off; off += n; return r; };
    // persistent floats
    float* omg    = alloc(NE);
    float* w0a    = alloc(NE);
    float* w1a    = alloc(NE);
    float* w2a    = alloc(NE);
    float* exA    = alloc(NEI);
    float* csr_a  = alloc(NE);
    float* csr_et = alloc(NE);
    float* segO   = alloc(N_ENT);
    float* denU   = alloc(N_USERS);
    float* c      = alloc(N_ITEMS);   // c and p adjacent -> single memset
    float* p      = alloc(64);
    float* v2     = alloc(64);
    float* cb     = alloc(64);
    float* RR1    = alloc(10 * D);
    float* PSI    = alloc(10 * D);
    // persistent ints (region starts 8B-aligned)
    if (off & 1) off++;
    int* IW = (int*)(W + off);
    size_t ioff = 0;
    auto ialloc = [&](size_t n) { int* r = IW + ioff; ioff += n; return r; };
    int2* csr_itw = (int2*)ialloc(2 * NEI);   // packed (item, wbits)
    int* csr_tr = ialloc(NE);
    int* cntU   = ialloc(N_USERS);            // cntU/cntH adjacent -> single memset
    int* cntH   = ialloc(N_ENT);
    int* offU   = ialloc(N_USERS + 1);
    int* curU   = ialloc(N_USERS);
    int* offH   = ialloc(N_ENT + 1);
    int* curH   = ialloc(N_ENT);
    int* bsumU  = ialloc(256);
    int* bsxU   = ialloc(257);
    int* bsumH  = ialloc(256);
    int* bsxH   = ialloc(257);
    off += ioff;
    // union region
    float* U = W + off;
    // phase A (within EH slot)
    bf16*  IkB = (bf16*)U;
    float* Iv  = U + (size_t)N_ITEMS * 32;
    float* Uq  = Iv + (size_t)N_ITEMS * D;
    // phase B
    float* EH  = U;
    float* ET  = EH + (size_t)N_ENT * D;
    float* PHI = U;                             // overwrites EH after omega1
    // phase C: eA over dead ET slot, eB over dead PHI slot
    bf16* eA = (bf16*)ET;
    bf16* eB = (bf16*)U;

    const int nbU = (N_USERS + 1023) / 1024;    // 49
    const int nbH = (N_ENT + 1023) / 1024;      // 98
    const int s3U = (N_USERS + 256) / 256;
    const int s3H = (N_ENT + 256) / 256;
    const int IB = (N_ITEMS + 63) / 64;
    const int UB = (N_USERS + 63) / 64;
    const int EB = (N_ENT + 63) / 64;
    const int OB = (N_ENT + 3) / 4;             // omega wave-blocks
    const int CB = (N_ENT * D) / 1024;          // cvt blocks (exact)
    const int HE = (N_ENT + 3) / 4;
    const int HU = (N_USERS + 3) / 4;

    // ---- CSR build ----
    hipMemsetAsync(cntU, 0, (N_USERS + N_ENT) * 4, stream);
    hipMemsetAsync(c, 0, (N_ITEMS + 64) * 4, stream);
    k_hist2<<<(NEI + NE + 255) / 256, 256, 0, stream>>>(inter_edge, edge_index, cntU, cntH);
    k_scan1<<<nbU + nbH, 256, 0, stream>>>(cntU, offU, bsumU, N_USERS, nbU,
                                           cntH, offH, bsumH, N_ENT);
    k_scan2<<<2, 256, 0, stream>>>(bsumU, bsxU, nbU, bsumH, bsxH, nbH);
    k_scan3<<<s3U + s3H, 256, 0, stream>>>(offU, curU, bsxU, N_USERS, nbU, s3U,
                                           offH, curH, bsxH, N_ENT, nbH);
    k_scatter<<<(NEI + NE + 255) / 256, 256, 0, stream>>>(inter_edge, inter_edge_w,
                                                          edge_index, edge_type,
                                                          curU, curH, csr_itw, csr_tr);

    // ---- Phase A ----
    k_proj<<<IB + UB, 256, 0, stream>>>(item_embed, Wk, Wv, user_embed, Wq,
                                        IkB, Iv, Uq, IB);
    k_userA<<<(N_USERS + 3) / 4, 256, 0, stream>>>(offU, csr_itw, Uq, IkB, exA, denU, N_USERS);
    k_userB<<<(N_USERS + 3) / 4, 256, 0, stream>>>(offU, csr_itw, exA, denU, c, N_USERS);
    k_pdense<<<64, 256, 0, stream>>>(c, Iv, p, N_ITEMS);

    // ---- Phase B ----
    k_entabx<<<EB + 2, 256, 0, stream>>>(ent_real, ent_imag, fp_W1, rel_real, rel_imag,
                                         rt_W1, rt_W2, rt_b2, p, EH, ET, RR1, PSI,
                                         v2, cb, EB);
    k_omega1<<<(N_ENT + 3) / 4, 256, 0, stream>>>(offH, csr_tr, EH, ET, RR1, fp_b1,
                                                  fp_W2, fp_b2, w0a, w1a, w2a, N_ENT);
    k_ent_phi<<<EB, 256, 0, stream>>>(ent_real, ent_imag, rt_W1, PHI, N_ENT);
    k_omega2a<<<OB + CB, 256, 0, stream>>>(offH, csr_tr, PHI, PSI, rt_b1, v2, cb,
                                           w0a, w1a, w2a, omg, segO,
                                           entity_emb, eA, OB, N_ENT);
    k_omega2b<<<(N_ENT + 3) / 4, 256, 0, stream>>>(offH, omg, segO, csr_a, csr_et, N_ENT);

    // ---- hops ----
    bf16* ecur = eA;
    bf16* enxt = eB;
    for (int hop = 1; hop <= 3; hop++) {
        const float* rho = (hop < 3) ? csr_a : csr_et;
        int init = (hop == 1) ? 1 : 0;
        k_hop<<<HE + HU, 256, 0, stream>>>(offH, csr_tr, rho, relation_emb,
                                           offU, csr_itw, ecur, enxt,
                                           entity_emb, user_emb,
                                           out, out + (size_t)N_ENT * D, init, HE);
        bf16* tmp = ecur; ecur = enxt; enxt = tmp;
    }
}